// Round 9
// baseline (166.142 us; speedup 1.0000x reference)
//
#include <hip/hip_runtime.h>
#include <hip/hip_bf16.h>

// Problem constants
#define DIMD   768
#define HEADS  16
#define HD     48
#define SEQ    2048
#define BATCH  4
#define NTOK   (BATCH * SEQ)     // 8192
#define QKVD   (3 * DIMD)        // 2304

typedef __attribute__((ext_vector_type(8)))  short s16x8;
typedef __attribute__((ext_vector_type(4)))  float f32x4;
typedef __attribute__((ext_vector_type(16))) float f32x16;
typedef unsigned short ushort_t;

static __device__ __forceinline__ unsigned short f2b(float f) {
  union { __hip_bfloat16 b; unsigned short s; } u;
  u.b = __float2bfloat16(f);
  return u.s;
}
static __device__ __forceinline__ float b2f(unsigned short v) {
  union { float f; unsigned u; } x;
  x.u = ((unsigned)v) << 16;
  return x.f;
}
static __device__ __forceinline__ unsigned pk2(float a, float b) {
  return (unsigned)f2b(a) | ((unsigned)f2b(b) << 16);
}

static __device__ __forceinline__ void gload_lds16(const void* g, void* l) {
  __builtin_amdgcn_global_load_lds(
      (const __attribute__((address_space(1))) unsigned int*)g,
      (__attribute__((address_space(3))) unsigned int*)l, 16, 0, 0);
}

// ---------------------------------------------------------------------------
// convert fp32 -> bf16 (row-major, 8 elems/thread)
// ---------------------------------------------------------------------------
__global__ __launch_bounds__(256) void cvt_bf16(const float* __restrict__ in,
                                                ushort_t* __restrict__ out, int n8) {
  int i = blockIdx.x * 256 + threadIdx.x;
  if (i >= n8) return;
  float4 a = ((const float4*)in)[i * 2];
  float4 b = ((const float4*)in)[i * 2 + 1];
  s16x8 v;
  v[0] = (short)f2b(a.x); v[1] = (short)f2b(a.y);
  v[2] = (short)f2b(a.z); v[3] = (short)f2b(a.w);
  v[4] = (short)f2b(b.x); v[5] = (short)f2b(b.y);
  v[6] = (short)f2b(b.z); v[7] = (short)f2b(b.w);
  ((s16x8*)out)[i] = v;
}

// ---------------------------------------------------------------------------
// transpose + convert: out[c][r] = bf16(in[r][c]); 32x32 LDS tiles
// ---------------------------------------------------------------------------
__global__ __launch_bounds__(256) void tcvt_bf16(const float* __restrict__ in,
                                                 ushort_t* __restrict__ out,
                                                 int R, int C) {
  __shared__ float T[32][33];
  const int c0 = blockIdx.x * 32, r0 = blockIdx.y * 32;
  const int lc = threadIdx.x & 31, lr = threadIdx.x >> 5;
#pragma unroll
  for (int i = 0; i < 4; ++i)
    T[lr + 8 * i][lc] = in[(size_t)(r0 + lr + 8 * i) * C + c0 + lc];
  __syncthreads();
#pragma unroll
  for (int i = 0; i < 4; ++i)
    out[(size_t)(c0 + lr + 8 * i) * R + r0 + lc] = f2b(T[lc][lr + 8 * i]);
}

// ---------------------------------------------------------------------------
// bf16 MFMA GEMM (m97 structure, unchanged)
// ---------------------------------------------------------------------------
template <int OUT_BF16>
__global__ __launch_bounds__(256) void gemm_bf16(
    const ushort_t* __restrict__ A, const ushort_t* __restrict__ Bt,
    const float* __restrict__ bias, void* __restrict__ Cout,
    int M, int N, int K) {
  __shared__ __align__(16) ushort_t As[128 * 64];
  __shared__ __align__(16) ushort_t Bs[128 * 64];

  const int tid = threadIdx.x;
  const int lane = tid & 63;
  const int w = tid >> 6;
  const int m0 = blockIdx.y * 128, n0 = blockIdx.x * 128;
  const int wm = (w >> 1) * 64, wn = (w & 1) * 64;

  const int c16s = (tid & 7) ^ ((tid >> 3) & 7);
  const ushort_t* aSrc = A + (size_t)(m0 + (tid >> 3)) * K + c16s * 8;
  const ushort_t* bSrc = Bt + (size_t)(n0 + (tid >> 3)) * K + c16s * 8;

  f32x4 acc[4][4];
#pragma unroll
  for (int i = 0; i < 4; ++i)
#pragma unroll
    for (int j = 0; j < 4; ++j) {
      acc[i][j][0] = 0.f; acc[i][j][1] = 0.f;
      acc[i][j][2] = 0.f; acc[i][j][3] = 0.f;
    }

  for (int k0 = 0; k0 < K; k0 += 64) {
    __syncthreads();
#pragma unroll
    for (int r = 0; r < 4; ++r) {
      gload_lds16(aSrc + (size_t)(r * 32) * K + k0,
                  (char*)As + (r * 256 + w * 64) * 16);
      gload_lds16(bSrc + (size_t)(r * 32) * K + k0,
                  (char*)Bs + (r * 256 + w * 64) * 16);
    }
    __syncthreads();

#pragma unroll
    for (int ks = 0; ks < 2; ++ks) {
      s16x8 af[4], bfr[4];
#pragma unroll
      for (int i = 0; i < 4; ++i) {
        const int ar = wm + i * 16 + (lane & 15);
        const int ac = (ks * 4 + (lane >> 4)) ^ (ar & 7);
        af[i] = *(const s16x8*)&As[ar * 64 + ac * 8];
        const int br = wn + i * 16 + (lane & 15);
        const int bc = (ks * 4 + (lane >> 4)) ^ (br & 7);
        bfr[i] = *(const s16x8*)&Bs[br * 64 + bc * 8];
      }
#pragma unroll
      for (int i = 0; i < 4; ++i)
#pragma unroll
        for (int j = 0; j < 4; ++j)
          acc[i][j] = __builtin_amdgcn_mfma_f32_16x16x32_bf16(
              af[i], bfr[j], acc[i][j], 0, 0, 0);
    }
  }

  if (OUT_BF16) {
    ushort_t* C = (ushort_t*)Cout;
#pragma unroll
    for (int i = 0; i < 4; ++i)
#pragma unroll
      for (int j = 0; j < 4; ++j) {
        const int col = n0 + wn + j * 16 + (lane & 15);
#pragma unroll
        for (int r = 0; r < 4; ++r) {
          const int row = m0 + wm + i * 16 + (lane >> 4) * 4 + r;
          C[(size_t)row * N + col] = f2b(acc[i][j][r]);
        }
      }
  } else {
    float* C = (float*)Cout;
#pragma unroll
    for (int i = 0; i < 4; ++i)
#pragma unroll
      for (int j = 0; j < 4; ++j) {
        const int col = n0 + wn + j * 16 + (lane & 15);
        const float bv = bias ? bias[col] : 0.f;
#pragma unroll
        for (int r = 0; r < 4; ++r) {
          const int row = m0 + wm + i * 16 + (lane >> 4) * 4 + r;
          C[(size_t)row * N + col] = acc[i][j][r] + bv;
        }
      }
  }
}

// ---------------------------------------------------------------------------
// bf16-MFMA flash attention, round 9:
//  round-7 math (raw exp2, no max, l via ones-row) and grid (64x8, 8 waves),
//  but KVB=128: stage a 128-key K/V double-tile per barrier pair, then run
//  TWO sequential 64-key compute passes with no barrier between. Halves the
//  per-block barrier count (64 -> 32) and staging phases; passes overlap in
//  the wave (pass1 QK/exp2 ILP with pass0 PV). Registers reused across
//  passes (s0/s1/pw), so VGPR footprint ~unchanged.
//  LDS: Kfrag 12 slots (12 KB) + Vt [64][128] (16 KB) = 28 KB.
// ---------------------------------------------------------------------------
#define QPW 32
#define QPB 256
#define NT2 (SEQ / 128)     // 16 double-tiles

__global__ __launch_bounds__(512) void attn_mfma(const ushort_t* __restrict__ QKV,
                                                 ushort_t* __restrict__ Aout) {
  const int bh = blockIdx.x;   // fast dim: q-tiles of one (b,h) share an XCD
  const int qt = blockIdx.y;
  const int b = bh >> 4, h = bh & 15;
  const int tid  = threadIdx.x;
  const int w    = tid >> 6;      // 0..7
  const int lane = tid & 63;
  const int l31  = lane & 31;
  const int hi   = lane >> 5;

  __shared__ __align__(16) ushort_t Kfrag[12 * 64 * 8];  // 12 KB [slot][pos^slot][8]
  __shared__ __align__(16) ushort_t Vt[64 * 128];        // 16 KB [hd(pad 64)][key 0..127]

  // pad rows: 49..63 zero; row 48 = 1.0 (ones row -> PV accumulates l)
  if (tid < 480) *(uint2*)&Vt[49 * 128 + tid * 4] = make_uint2(0u, 0u);
  if (tid < 128) Vt[48 * 128 + tid] = (ushort_t)0x3F80;  // bf16(1.0), row 48 unswizzled

  const ushort_t* qkv_b = QKV + (size_t)b * SEQ * QKVD;

  // --- Q fragments, pre-scaled by SCALE*log2(e) ---
  const float qs = 0.14433756729740643f * 1.44269504088896340f;
  const int qrow = qt * QPB + w * QPW + l31;
  const ushort_t* qsrc = qkv_b + (size_t)qrow * QKVD + h * HD;
  s16x8 qf[3];
#pragma unroll
  for (int ks = 0; ks < 3; ++ks) {
    s16x8 raw = *(const s16x8*)(qsrc + ks * 16 + hi * 8);
    s16x8 v;
#pragma unroll
    for (int j = 0; j < 8; ++j) v[j] = (short)f2b(b2f((unsigned short)raw[j]) * qs);
    qf[ks] = v;
  }

  f32x16 o[2];
#pragma unroll
  for (int mt = 0; mt < 2; ++mt)
#pragma unroll
    for (int r = 0; r < 16; ++r) o[mt][r] = 0.f;

  // staging slices: slice s in 0..11 -> key-half = s/6, hd-granule g = s%6.
  // wave w owns slice w; waves 0..3 also own slice w+8.
  const int halfA = (w >= 6) ? 1 : 0;
  const int gA    = w - 6 * halfA;
  const int keyA  = lane + 64 * halfA;        // key row within 128
  const int gB    = w + 2;                    // only for w<4 (slices 8..11, half 1)
  const int keyB  = lane + 64;

  const ushort_t* kvA = qkv_b + (size_t)keyA * QKVD + DIMD + h * HD;
  const ushort_t* kvB = qkv_b + (size_t)keyB * QKVD + DIMD + h * HD;

  s16x8 ka, va, kb, vb;
  auto loadKV = [&](int it) {
    const size_t off = (size_t)(it * 128) * QKVD;
    ka = *(const s16x8*)(kvA + off + gA * 8);
    va = *(const s16x8*)(kvA + off + DIMD + gA * 8);
    if (w < 4) {
      kb = *(const s16x8*)(kvB + off + gB * 8);
      vb = *(const s16x8*)(kvB + off + DIMD + gB * 8);
    }
  };
  auto writeKV = [&]() {
    {
      const int slot = (keyA >> 5) * 3 + (gA >> 1);
      const int pos = (((keyA & 31) + ((gA & 1) << 5)) ^ slot);
      *(s16x8*)&Kfrag[(slot * 64 + pos) * 8] = ka;
#pragma unroll
      for (int j = 0; j < 8; ++j)
        Vt[(8 * gA + j) * 128 + (keyA ^ (j << 3))] = (ushort_t)va[j];
    }
    if (w < 4) {
      const int slot = (keyB >> 5) * 3 + (gB >> 1);
      const int pos = (((keyB & 31) + ((gB & 1) << 5)) ^ slot);
      *(s16x8*)&Kfrag[(slot * 64 + pos) * 8] = kb;
#pragma unroll
      for (int j = 0; j < 8; ++j)
        Vt[(8 * gB + j) * 128 + (keyB ^ (j << 3))] = (ushort_t)vb[j];
    }
  };

  loadKV(0);

  for (int it = 0; it < NT2; ++it) {
    __syncthreads();   // LDS readers of previous double-tile done
    writeKV();
    __syncthreads();   // 128-key tile ready
    if (it + 1 < NT2) loadKV(it + 1);   // T14: lands during the two passes

#pragma unroll
    for (int h2 = 0; h2 < 2; ++h2) {
      // ---- QK^T swapped: S^T[key][q], key blocks 2*h2, 2*h2+1 ----
      f32x16 s0, s1;
#pragma unroll
      for (int r = 0; r < 16; ++r) { s0[r] = 0.f; s1[r] = 0.f; }
      __builtin_amdgcn_s_setprio(1);
#pragma unroll
      for (int ks = 0; ks < 3; ++ks) {
        const int sl0 = 6 * h2 + ks;
        s16x8 a0 = *(const s16x8*)&Kfrag[(sl0 * 64 + (lane ^ sl0)) * 8];
        s0 = __builtin_amdgcn_mfma_f32_32x32x16_bf16(a0, qf[ks], s0, 0, 0, 0);
        const int sl1 = 6 * h2 + 3 + ks;
        s16x8 a1 = *(const s16x8*)&Kfrag[(sl1 * 64 + (lane ^ sl1)) * 8];
        s1 = __builtin_amdgcn_mfma_f32_32x32x16_bf16(a1, qf[ks], s1, 0, 0, 0);
      }
      __builtin_amdgcn_s_setprio(0);

      // ---- softmax numerator: exp2 raw (logits bounded), pack to bf16 ----
      unsigned pw0[8], pw1[8];
#pragma unroll
      for (int g = 0; g < 8; ++g) {
        pw0[g] = pk2(__builtin_amdgcn_exp2f(s0[2 * g]),
                     __builtin_amdgcn_exp2f(s0[2 * g + 1]));
        pw1[g] = pk2(__builtin_amdgcn_exp2f(s1[2 * g]),
                     __builtin_amdgcn_exp2f(s1[2 * g + 1]));
      }

      // ---- PV: O^T += V^T @ P^T ; P^T B-frags via permlane32_swap ----
      __builtin_amdgcn_s_setprio(1);
#pragma unroll
      for (int ks = 0; ks < 4; ++ks) {
        unsigned w0 = (ks < 2) ? pw0[4 * (ks & 1) + 0] : pw1[4 * (ks & 1) + 0];
        unsigned w1 = (ks < 2) ? pw0[4 * (ks & 1) + 1] : pw1[4 * (ks & 1) + 1];
        unsigned w2 = (ks < 2) ? pw0[4 * (ks & 1) + 2] : pw1[4 * (ks & 1) + 2];
        unsigned w3 = (ks < 2) ? pw0[4 * (ks & 1) + 3] : pw1[4 * (ks & 1) + 3];
        asm("v_permlane32_swap_b32 %0, %1" : "+v"(w0), "+v"(w2));
        asm("v_permlane32_swap_b32 %0, %1" : "+v"(w1), "+v"(w3));
        union { unsigned u[4]; s16x8 v; } pf;
        pf.u[0] = w0; pf.u[1] = w1; pf.u[2] = w2; pf.u[3] = w3;
        const int keyb = h2 * 64 + ks * 16 + hi * 8;
#pragma unroll
        for (int mt = 0; mt < 2; ++mt) {
          const int hd = mt * 32 + l31;
          s16x8 vfrag = *(const s16x8*)&Vt[hd * 128 + (keyb ^ ((hd & 7) << 3))];
          o[mt] = __builtin_amdgcn_mfma_f32_32x32x16_bf16(vfrag, pf.v, o[mt], 0, 0, 0);
        }
      }
      __builtin_amdgcn_s_setprio(0);
    }
  }

  // ---- epilogue: l = o[1][8] (hd 48 = ones row, hi=0 half); normalize ----
  const float lsum = __shfl(o[1][8], l31, 64);
  const float inv = 1.f / lsum;
  const int token = qt * QPB + w * QPW + l31;
  ushort_t* dst = Aout + ((size_t)b * SEQ + token) * DIMD + h * HD;
#pragma unroll
  for (int rq = 0; rq < 4; ++rq) {      // m-tile0: hd = 8*rq + 4*hi + {0..3}
    const int hd0 = 8 * rq + 4 * hi;
    uint2 pk;
    pk.x = pk2(o[0][4 * rq + 0] * inv, o[0][4 * rq + 1] * inv);
    pk.y = pk2(o[0][4 * rq + 2] * inv, o[0][4 * rq + 3] * inv);
    *(uint2*)(dst + hd0) = pk;
  }
#pragma unroll
  for (int rq = 0; rq < 2; ++rq) {      // m-tile1: hd = 32 + 8*rq + 4*hi + {0..3}
    const int hd0 = 32 + 8 * rq + 4 * hi;
    uint2 pk;
    pk.x = pk2(o[1][4 * rq + 0] * inv, o[1][4 * rq + 1] * inv);
    pk.y = pk2(o[1][4 * rq + 2] * inv, o[1][4 * rq + 3] * inv);
    *(uint2*)(dst + hd0) = pk;
  }
}

// ---------------------------------------------------------------------------
extern "C" void kernel_launch(void* const* d_in, const int* in_sizes, int n_in,
                              void* d_out, int out_size, void* d_ws, size_t ws_size,
                              hipStream_t stream) {
  const float* x      = (const float*)d_in[0];
  const float* w_qkv  = (const float*)d_in[1];
  const float* w_proj = (const float*)d_in[2];
  const float* b_proj = (const float*)d_in[3];
  float* out = (float*)d_out;

  ushort_t* xb     = (ushort_t*)d_ws;                  // [8192,768]  bf16
  ushort_t* wqkvT  = xb + (size_t)NTOK * DIMD;         // [2304,768]  bf16 (T)
  ushort_t* wprojT = wqkvT + (size_t)QKVD * DIMD;      // [768,768]   bf16 (T)
  ushort_t* qkv    = wprojT + (size_t)DIMD * DIMD;     // [8192,2304] bf16
  ushort_t* att    = qkv + (size_t)NTOK * QKVD;        // [8192,768]  bf16

  cvt_bf16<<<(NTOK * DIMD / 8 + 255) / 256, 256, 0, stream>>>(x, xb, NTOK * DIMD / 8);
  tcvt_bf16<<<dim3(QKVD / 32, DIMD / 32), 256, 0, stream>>>(w_qkv, wqkvT, DIMD, QKVD);
  tcvt_bf16<<<dim3(DIMD / 32, DIMD / 32), 256, 0, stream>>>(w_proj, wprojT, DIMD, DIMD);

  gemm_bf16<1><<<dim3(QKVD / 128, NTOK / 128), 256, 0, stream>>>(
      xb, wqkvT, nullptr, qkv, NTOK, QKVD, DIMD);

  attn_mfma<<<dim3(BATCH * HEADS, SEQ / QPB), 512, 0, stream>>>(qkv, att);

  gemm_bf16<0><<<dim3(DIMD / 128, NTOK / 128), 256, 0, stream>>>(
      att, wprojT, b_proj, out, NTOK, DIMD, DIMD);
}

// Round 11
// 151.791 us; speedup vs baseline: 1.0945x; 1.0945x over previous
//
#include <hip/hip_runtime.h>
#include <hip/hip_bf16.h>

// Problem constants
#define DIMD   768
#define HEADS  16
#define HD     48
#define SEQ    2048
#define BATCH  4
#define NTOK   (BATCH * SEQ)     // 8192
#define QKVD   (3 * DIMD)        // 2304

typedef __attribute__((ext_vector_type(8)))  short s16x8;
typedef __attribute__((ext_vector_type(4)))  float f32x4;
typedef __attribute__((ext_vector_type(16))) float f32x16;
typedef unsigned short ushort_t;

static __device__ __forceinline__ unsigned short f2b(float f) {
  union { __hip_bfloat16 b; unsigned short s; } u;
  u.b = __float2bfloat16(f);
  return u.s;
}
static __device__ __forceinline__ float b2f(unsigned short v) {
  union { float f; unsigned u; } x;
  x.u = ((unsigned)v) << 16;
  return x.f;
}
static __device__ __forceinline__ unsigned pk2(float a, float b) {
  return (unsigned)f2b(a) | ((unsigned)f2b(b) << 16);
}

static __device__ __forceinline__ void gload_lds16(const void* g, void* l) {
  __builtin_amdgcn_global_load_lds(
      (const __attribute__((address_space(1))) unsigned int*)g,
      (__attribute__((address_space(3))) unsigned int*)l, 16, 0, 0);
}

// ---------------------------------------------------------------------------
// convert fp32 -> bf16 (row-major, 8 elems/thread)
// ---------------------------------------------------------------------------
__global__ __launch_bounds__(256) void cvt_bf16(const float* __restrict__ in,
                                                ushort_t* __restrict__ out, int n8) {
  int i = blockIdx.x * 256 + threadIdx.x;
  if (i >= n8) return;
  float4 a = ((const float4*)in)[i * 2];
  float4 b = ((const float4*)in)[i * 2 + 1];
  s16x8 v;
  v[0] = (short)f2b(a.x); v[1] = (short)f2b(a.y);
  v[2] = (short)f2b(a.z); v[3] = (short)f2b(a.w);
  v[4] = (short)f2b(b.x); v[5] = (short)f2b(b.y);
  v[6] = (short)f2b(b.z); v[7] = (short)f2b(b.w);
  ((s16x8*)out)[i] = v;
}

// ---------------------------------------------------------------------------
// transpose + convert: out[c][r] = bf16(in[r][c]); 32x32 LDS tiles
// ---------------------------------------------------------------------------
__global__ __launch_bounds__(256) void tcvt_bf16(const float* __restrict__ in,
                                                 ushort_t* __restrict__ out,
                                                 int R, int C) {
  __shared__ float T[32][33];
  const int c0 = blockIdx.x * 32, r0 = blockIdx.y * 32;
  const int lc = threadIdx.x & 31, lr = threadIdx.x >> 5;
#pragma unroll
  for (int i = 0; i < 4; ++i)
    T[lr + 8 * i][lc] = in[(size_t)(r0 + lr + 8 * i) * C + c0 + lc];
  __syncthreads();
#pragma unroll
  for (int i = 0; i < 4; ++i)
    out[(size_t)(c0 + lr + 8 * i) * R + r0 + lc] = f2b(T[lc][lr + 8 * i]);
}

// ---------------------------------------------------------------------------
// bf16 MFMA GEMM (m97 structure, unchanged)
// ---------------------------------------------------------------------------
template <int OUT_BF16>
__global__ __launch_bounds__(256) void gemm_bf16(
    const ushort_t* __restrict__ A, const ushort_t* __restrict__ Bt,
    const float* __restrict__ bias, void* __restrict__ Cout,
    int M, int N, int K) {
  __shared__ __align__(16) ushort_t As[128 * 64];
  __shared__ __align__(16) ushort_t Bs[128 * 64];

  const int tid = threadIdx.x;
  const int lane = tid & 63;
  const int w = tid >> 6;
  const int m0 = blockIdx.y * 128, n0 = blockIdx.x * 128;
  const int wm = (w >> 1) * 64, wn = (w & 1) * 64;

  const int c16s = (tid & 7) ^ ((tid >> 3) & 7);
  const ushort_t* aSrc = A + (size_t)(m0 + (tid >> 3)) * K + c16s * 8;
  const ushort_t* bSrc = Bt + (size_t)(n0 + (tid >> 3)) * K + c16s * 8;

  f32x4 acc[4][4];
#pragma unroll
  for (int i = 0; i < 4; ++i)
#pragma unroll
    for (int j = 0; j < 4; ++j) {
      acc[i][j][0] = 0.f; acc[i][j][1] = 0.f;
      acc[i][j][2] = 0.f; acc[i][j][3] = 0.f;
    }

  for (int k0 = 0; k0 < K; k0 += 64) {
    __syncthreads();
#pragma unroll
    for (int r = 0; r < 4; ++r) {
      gload_lds16(aSrc + (size_t)(r * 32) * K + k0,
                  (char*)As + (r * 256 + w * 64) * 16);
      gload_lds16(bSrc + (size_t)(r * 32) * K + k0,
                  (char*)Bs + (r * 256 + w * 64) * 16);
    }
    __syncthreads();

#pragma unroll
    for (int ks = 0; ks < 2; ++ks) {
      s16x8 af[4], bfr[4];
#pragma unroll
      for (int i = 0; i < 4; ++i) {
        const int ar = wm + i * 16 + (lane & 15);
        const int ac = (ks * 4 + (lane >> 4)) ^ (ar & 7);
        af[i] = *(const s16x8*)&As[ar * 64 + ac * 8];
        const int br = wn + i * 16 + (lane & 15);
        const int bc = (ks * 4 + (lane >> 4)) ^ (br & 7);
        bfr[i] = *(const s16x8*)&Bs[br * 64 + bc * 8];
      }
#pragma unroll
      for (int i = 0; i < 4; ++i)
#pragma unroll
        for (int j = 0; j < 4; ++j)
          acc[i][j] = __builtin_amdgcn_mfma_f32_16x16x32_bf16(
              af[i], bfr[j], acc[i][j], 0, 0, 0);
    }
  }

  if (OUT_BF16) {
    ushort_t* C = (ushort_t*)Cout;
#pragma unroll
    for (int i = 0; i < 4; ++i)
#pragma unroll
      for (int j = 0; j < 4; ++j) {
        const int col = n0 + wn + j * 16 + (lane & 15);
#pragma unroll
        for (int r = 0; r < 4; ++r) {
          const int row = m0 + wm + i * 16 + (lane >> 4) * 4 + r;
          C[(size_t)row * N + col] = f2b(acc[i][j][r]);
        }
      }
  } else {
    float* C = (float*)Cout;
#pragma unroll
    for (int i = 0; i < 4; ++i)
#pragma unroll
      for (int j = 0; j < 4; ++j) {
        const int col = n0 + wn + j * 16 + (lane & 15);
        const float bv = bias ? bias[col] : 0.f;
#pragma unroll
        for (int r = 0; r < 4; ++r) {
          const int row = m0 + wm + i * 16 + (lane >> 4) * 4 + r;
          C[(size_t)row * N + col] = acc[i][j][r] + bv;
        }
      }
  }
}

// ---------------------------------------------------------------------------
// bf16-MFMA flash attention, round 11 = round 10 + the missing barrier
// between the Vt2 zero-init and the ones-row write (round 10's failure was a
// write-write race on row 48: the blanket zero of the whole buffer raced the
// ones-row stores from other threads). Layout unchanged:
//   Vt2[(kb*65 + hd)*8 + key%8], kb = key/8, row pad 65 -> the PV b128 read
//   is 32 consecutive 16B slots per half-wave (conflict-free); writes 2/bank.
// Arithmetic bit-identical to round 7.
// ---------------------------------------------------------------------------
#define KVB 64
#define QPW 32
#define QPB 256
#define NT  (SEQ / KVB)

__global__ __launch_bounds__(512) void attn_mfma(const ushort_t* __restrict__ QKV,
                                                 ushort_t* __restrict__ Aout) {
  const int bh = blockIdx.x;   // fast dim: q-tiles of one (b,h) share an XCD
  const int qt = blockIdx.y;
  const int b = bh >> 4, h = bh & 15;
  const int tid  = threadIdx.x;
  const int w    = tid >> 6;      // 0..7
  const int lane = tid & 63;
  const int l31  = lane & 31;
  const int hi   = lane >> 5;

  __shared__ __align__(16) ushort_t Kfrag[6 * 64 * 8];  // 6 KB [slot][pos^slot][8]
  __shared__ __align__(16) ushort_t Vt2[8 * 65 * 8];    // 8.1 KB [kb][hd(pad65)][key%8]

  // zero the whole Vt2, BARRIER, then ones row hd=48 (r10 bug: no barrier ->
  // zeroing of row-48 slots raced the ones-row stores).
  *(uint4*)&Vt2[tid * 8] = make_uint4(0u, 0u, 0u, 0u);          // bytes 0..8191
  if (tid < 8) *(uint4*)&Vt2[4096 + tid * 8] = make_uint4(0u, 0u, 0u, 0u);
  __syncthreads();
  if (tid < 64) Vt2[((tid >> 3) * 65 + 48) * 8 + (tid & 7)] = (ushort_t)0x3F80;

  const ushort_t* qkv_b = QKV + (size_t)b * SEQ * QKVD;

  // --- Q fragments, pre-scaled by SCALE*log2(e) ---
  const float qs = 0.14433756729740643f * 1.44269504088896340f;
  const int qrow = qt * QPB + w * QPW + l31;
  const ushort_t* qsrc = qkv_b + (size_t)qrow * QKVD + h * HD;
  s16x8 qf[3];
#pragma unroll
  for (int ks = 0; ks < 3; ++ks) {
    s16x8 raw = *(const s16x8*)(qsrc + ks * 16 + hi * 8);
    s16x8 v;
#pragma unroll
    for (int j = 0; j < 8; ++j) v[j] = (short)f2b(b2f((unsigned short)raw[j]) * qs);
    qf[ks] = v;
  }

  f32x16 o[2];
#pragma unroll
  for (int mt = 0; mt < 2; ++mt)
#pragma unroll
    for (int r = 0; r < 16; ++r) o[mt][r] = 0.f;

  // staging: lane = key row; wave w = hd-granule (waves 0..5 only)
  const int srow = lane;
  const int g0 = w;
  const ushort_t* kv0 = qkv_b + (size_t)srow * QKVD + DIMD + h * HD;

  s16x8 ka, va;
  auto loadKV = [&](int kt) {
    if (g0 < 6) {
      const ushort_t* base = kv0 + (size_t)(kt * KVB) * QKVD;
      ka = *(const s16x8*)(base + g0 * 8);
      va = *(const s16x8*)(base + DIMD + g0 * 8);
    }
  };
  auto writeKV = [&]() {
    if (g0 < 6) {
      const int slot = (srow >> 5) * 3 + (g0 >> 1);
      const int pos = (((srow & 31) + ((g0 & 1) << 5)) ^ slot);
      *(s16x8*)&Kfrag[(slot * 64 + pos) * 8] = ka;
      const int kb = srow >> 3, k7 = srow & 7;
#pragma unroll
      for (int j = 0; j < 8; ++j)
        Vt2[(kb * 65 + 8 * g0 + j) * 8 + k7] = (ushort_t)va[j];
    }
  };

  loadKV(0);

  for (int kt = 0; kt < NT; ++kt) {
    __syncthreads();   // LDS readers of previous tile done
    writeKV();
    __syncthreads();   // K/V tile ready
    if (kt + 1 < NT) loadKV(kt + 1);   // T14: lands during compute

    // ---- QK^T swapped: S^T[key][q], two 32-key halves ----
    f32x16 s0, s1;
#pragma unroll
    for (int r = 0; r < 16; ++r) { s0[r] = 0.f; s1[r] = 0.f; }
    __builtin_amdgcn_s_setprio(1);
#pragma unroll
    for (int ks = 0; ks < 3; ++ks) {
      s16x8 a0 = *(const s16x8*)&Kfrag[(ks * 64 + (lane ^ ks)) * 8];
      s0 = __builtin_amdgcn_mfma_f32_32x32x16_bf16(a0, qf[ks], s0, 0, 0, 0);
      s16x8 a1 = *(const s16x8*)&Kfrag[((3 + ks) * 64 + (lane ^ (3 + ks))) * 8];
      s1 = __builtin_amdgcn_mfma_f32_32x32x16_bf16(a1, qf[ks], s1, 0, 0, 0);
    }
    __builtin_amdgcn_s_setprio(0);

    // ---- softmax numerator: exp2 raw (logits bounded), pack to bf16 ----
    unsigned pw0[8], pw1[8];
#pragma unroll
    for (int g = 0; g < 8; ++g) {
      pw0[g] = pk2(__builtin_amdgcn_exp2f(s0[2 * g]),
                   __builtin_amdgcn_exp2f(s0[2 * g + 1]));
      pw1[g] = pk2(__builtin_amdgcn_exp2f(s1[2 * g]),
                   __builtin_amdgcn_exp2f(s1[2 * g + 1]));
    }

    // ---- PV: O^T += V^T @ P^T ; P^T B-frags via permlane32_swap ----
    __builtin_amdgcn_s_setprio(1);
#pragma unroll
    for (int ks = 0; ks < 4; ++ks) {
      unsigned w0 = (ks < 2) ? pw0[4 * (ks & 1) + 0] : pw1[4 * (ks & 1) + 0];
      unsigned w1 = (ks < 2) ? pw0[4 * (ks & 1) + 1] : pw1[4 * (ks & 1) + 1];
      unsigned w2 = (ks < 2) ? pw0[4 * (ks & 1) + 2] : pw1[4 * (ks & 1) + 2];
      unsigned w3 = (ks < 2) ? pw0[4 * (ks & 1) + 3] : pw1[4 * (ks & 1) + 3];
      asm("v_permlane32_swap_b32 %0, %1" : "+v"(w0), "+v"(w2));
      asm("v_permlane32_swap_b32 %0, %1" : "+v"(w1), "+v"(w3));
      union { unsigned u[4]; s16x8 v; } pf;
      pf.u[0] = w0; pf.u[1] = w1; pf.u[2] = w2; pf.u[3] = w3;
      const int kb = 2 * ks + hi;   // key-block = (ks*16 + hi*8) / 8
#pragma unroll
      for (int mt = 0; mt < 2; ++mt) {
        const int hd = mt * 32 + l31;
        s16x8 vfrag = *(const s16x8*)&Vt2[(kb * 65 + hd) * 8];
        o[mt] = __builtin_amdgcn_mfma_f32_32x32x16_bf16(vfrag, pf.v, o[mt], 0, 0, 0);
      }
    }
    __builtin_amdgcn_s_setprio(0);
  }

  // ---- epilogue: l = o[1][8] (hd 48 = ones row, hi=0 half); normalize ----
  const float lsum = __shfl(o[1][8], l31, 64);
  const float inv = 1.f / lsum;
  const int token = qt * QPB + w * QPW + l31;
  ushort_t* dst = Aout + ((size_t)b * SEQ + token) * DIMD + h * HD;
#pragma unroll
  for (int rq = 0; rq < 4; ++rq) {      // m-tile0: hd = 8*rq + 4*hi + {0..3}
    const int hd0 = 8 * rq + 4 * hi;
    uint2 pk;
    pk.x = pk2(o[0][4 * rq + 0] * inv, o[0][4 * rq + 1] * inv);
    pk.y = pk2(o[0][4 * rq + 2] * inv, o[0][4 * rq + 3] * inv);
    *(uint2*)(dst + hd0) = pk;
  }
#pragma unroll
  for (int rq = 0; rq < 2; ++rq) {      // m-tile1: hd = 32 + 8*rq + 4*hi + {0..3}
    const int hd0 = 32 + 8 * rq + 4 * hi;
    uint2 pk;
    pk.x = pk2(o[1][4 * rq + 0] * inv, o[1][4 * rq + 1] * inv);
    pk.y = pk2(o[1][4 * rq + 2] * inv, o[1][4 * rq + 3] * inv);
    *(uint2*)(dst + hd0) = pk;
  }
}

// ---------------------------------------------------------------------------
extern "C" void kernel_launch(void* const* d_in, const int* in_sizes, int n_in,
                              void* d_out, int out_size, void* d_ws, size_t ws_size,
                              hipStream_t stream) {
  const float* x      = (const float*)d_in[0];
  const float* w_qkv  = (const float*)d_in[1];
  const float* w_proj = (const float*)d_in[2];
  const float* b_proj = (const float*)d_in[3];
  float* out = (float*)d_out;

  ushort_t* xb     = (ushort_t*)d_ws;                  // [8192,768]  bf16
  ushort_t* wqkvT  = xb + (size_t)NTOK * DIMD;         // [2304,768]  bf16 (T)
  ushort_t* wprojT = wqkvT + (size_t)QKVD * DIMD;      // [768,768]   bf16 (T)
  ushort_t* qkv    = wprojT + (size_t)DIMD * DIMD;     // [8192,2304] bf16
  ushort_t* att    = qkv + (size_t)NTOK * QKVD;        // [8192,768]  bf16

  cvt_bf16<<<(NTOK * DIMD / 8 + 255) / 256, 256, 0, stream>>>(x, xb, NTOK * DIMD / 8);
  tcvt_bf16<<<dim3(QKVD / 32, DIMD / 32), 256, 0, stream>>>(w_qkv, wqkvT, DIMD, QKVD);
  tcvt_bf16<<<dim3(DIMD / 32, DIMD / 32), 256, 0, stream>>>(w_proj, wprojT, DIMD, DIMD);

  gemm_bf16<1><<<dim3(QKVD / 128, NTOK / 128), 256, 0, stream>>>(
      xb, wqkvT, nullptr, qkv, NTOK, QKVD, DIMD);

  attn_mfma<<<dim3(BATCH * HEADS, SEQ / QPB), 512, 0, stream>>>(qkv, att);

  gemm_bf16<0><<<dim3(DIMD / 128, NTOK / 128), 256, 0, stream>>>(
      att, wprojT, b_proj, out, NTOK, DIMD, DIMD);
}

// Round 12
// 140.846 us; speedup vs baseline: 1.1796x; 1.0777x over previous
//
#include <hip/hip_runtime.h>
#include <hip/hip_bf16.h>

// Problem constants
#define DIMD   768
#define HEADS  16
#define HD     48
#define SEQ    2048
#define BATCH  4
#define NTOK   (BATCH * SEQ)     // 8192
#define QKVD   (3 * DIMD)        // 2304

typedef __attribute__((ext_vector_type(8)))  short s16x8;
typedef __attribute__((ext_vector_type(4)))  float f32x4;
typedef __attribute__((ext_vector_type(16))) float f32x16;
typedef unsigned short ushort_t;

static __device__ __forceinline__ unsigned short f2b(float f) {
  union { __hip_bfloat16 b; unsigned short s; } u;
  u.b = __float2bfloat16(f);
  return u.s;
}
static __device__ __forceinline__ float b2f(unsigned short v) {
  union { float f; unsigned u; } x;
  x.u = ((unsigned)v) << 16;
  return x.f;
}
static __device__ __forceinline__ unsigned pk2(float a, float b) {
  return (unsigned)f2b(a) | ((unsigned)f2b(b) << 16);
}

static __device__ __forceinline__ void gload_lds16(const void* g, void* l) {
  __builtin_amdgcn_global_load_lds(
      (const __attribute__((address_space(1))) unsigned int*)g,
      (__attribute__((address_space(3))) unsigned int*)l, 16, 0, 0);
}

// ---------------------------------------------------------------------------
// merged convert kernel: one launch does
//   blocks [0, 3072)        : x fp32 -> bf16 row-major (8 elems/thread)
//   blocks [3072, 4800)     : w_qkv transpose+cvt  [768][2304] -> [2304][768]
//   blocks [4800, 5376)     : w_proj transpose+cvt [768][768]  -> [768][768]
// ---------------------------------------------------------------------------
#define CVT_NB   (NTOK * DIMD / 8 / 256)          // 3072
#define TQ_NBX   (QKVD / 32)                      // 72
#define TQ_NB    (TQ_NBX * (DIMD / 32))           // 1728
#define TP_NBX   (DIMD / 32)                      // 24
#define TP_NB    (TP_NBX * (DIMD / 32))           // 576

__global__ __launch_bounds__(256) void cvt_all(
    const float* __restrict__ x, ushort_t* __restrict__ xb,
    const float* __restrict__ wq, ushort_t* __restrict__ wqT,
    const float* __restrict__ wp, ushort_t* __restrict__ wpT) {
  __shared__ float T[32][33];
  const int bid = blockIdx.x;
  const int tid = threadIdx.x;

  if (bid < CVT_NB) {
    const int i = bid * 256 + tid;                // < NTOK*DIMD/8 exactly
    float4 a = ((const float4*)x)[i * 2];
    float4 b = ((const float4*)x)[i * 2 + 1];
    s16x8 v;
    v[0] = (short)f2b(a.x); v[1] = (short)f2b(a.y);
    v[2] = (short)f2b(a.z); v[3] = (short)f2b(a.w);
    v[4] = (short)f2b(b.x); v[5] = (short)f2b(b.y);
    v[6] = (short)f2b(b.z); v[7] = (short)f2b(b.w);
    ((s16x8*)xb)[i] = v;
    return;
  }

  const float* in;
  ushort_t* out;
  int R, C, c0, r0;
  if (bid < CVT_NB + TQ_NB) {
    const int b1 = bid - CVT_NB;
    in = wq; out = wqT; R = DIMD; C = QKVD;
    c0 = (b1 % TQ_NBX) * 32; r0 = (b1 / TQ_NBX) * 32;
  } else {
    const int b2 = bid - CVT_NB - TQ_NB;
    in = wp; out = wpT; R = DIMD; C = DIMD;
    c0 = (b2 % TP_NBX) * 32; r0 = (b2 / TP_NBX) * 32;
  }
  const int lc = tid & 31, lr = tid >> 5;
#pragma unroll
  for (int i = 0; i < 4; ++i)
    T[lr + 8 * i][lc] = in[(size_t)(r0 + lr + 8 * i) * C + c0 + lc];
  __syncthreads();
#pragma unroll
  for (int i = 0; i < 4; ++i)
    out[(size_t)(c0 + lr + 8 * i) * R + r0 + lc] = f2b(T[lc][lr + 8 * i]);
}

// ---------------------------------------------------------------------------
// bf16 MFMA GEMM (m97 structure) + T1 XCD-bijective block swizzle:
// HW assigns block orig -> XCD orig%8; remap so each XCD processes a
// CONTIGUOUS range of (m,n) tiles (8 m-rows x all n) -> A/B panels stay
// L2-resident per XCD. Bijective since grid counts are multiples of 8.
// ---------------------------------------------------------------------------
template <int OUT_BF16>
__global__ __launch_bounds__(256) void gemm_bf16(
    const ushort_t* __restrict__ A, const ushort_t* __restrict__ Bt,
    const float* __restrict__ bias, void* __restrict__ Cout,
    int M, int N, int K) {
  __shared__ __align__(16) ushort_t As[128 * 64];
  __shared__ __align__(16) ushort_t Bs[128 * 64];

  const int tid = threadIdx.x;
  const int lane = tid & 63;
  const int w = tid >> 6;

  // --- XCD swizzle (identity if grid not divisible by 8) ---
  const int nwg = gridDim.x * gridDim.y;
  int bx = blockIdx.x, by = blockIdx.y;
  if ((nwg & 7) == 0) {
    const int orig = by * gridDim.x + bx;
    const int cpx = nwg >> 3;
    const int nid = (orig & 7) * cpx + (orig >> 3);
    bx = nid % gridDim.x;
    by = nid / gridDim.x;
  }
  const int m0 = by * 128, n0 = bx * 128;
  const int wm = (w >> 1) * 64, wn = (w & 1) * 64;

  const int c16s = (tid & 7) ^ ((tid >> 3) & 7);
  const ushort_t* aSrc = A + (size_t)(m0 + (tid >> 3)) * K + c16s * 8;
  const ushort_t* bSrc = Bt + (size_t)(n0 + (tid >> 3)) * K + c16s * 8;

  f32x4 acc[4][4];
#pragma unroll
  for (int i = 0; i < 4; ++i)
#pragma unroll
    for (int j = 0; j < 4; ++j) {
      acc[i][j][0] = 0.f; acc[i][j][1] = 0.f;
      acc[i][j][2] = 0.f; acc[i][j][3] = 0.f;
    }

  for (int k0 = 0; k0 < K; k0 += 64) {
    __syncthreads();
#pragma unroll
    for (int r = 0; r < 4; ++r) {
      gload_lds16(aSrc + (size_t)(r * 32) * K + k0,
                  (char*)As + (r * 256 + w * 64) * 16);
      gload_lds16(bSrc + (size_t)(r * 32) * K + k0,
                  (char*)Bs + (r * 256 + w * 64) * 16);
    }
    __syncthreads();

#pragma unroll
    for (int ks = 0; ks < 2; ++ks) {
      s16x8 af[4], bfr[4];
#pragma unroll
      for (int i = 0; i < 4; ++i) {
        const int ar = wm + i * 16 + (lane & 15);
        const int ac = (ks * 4 + (lane >> 4)) ^ (ar & 7);
        af[i] = *(const s16x8*)&As[ar * 64 + ac * 8];
        const int br = wn + i * 16 + (lane & 15);
        const int bc = (ks * 4 + (lane >> 4)) ^ (br & 7);
        bfr[i] = *(const s16x8*)&Bs[br * 64 + bc * 8];
      }
#pragma unroll
      for (int i = 0; i < 4; ++i)
#pragma unroll
        for (int j = 0; j < 4; ++j)
          acc[i][j] = __builtin_amdgcn_mfma_f32_16x16x32_bf16(
              af[i], bfr[j], acc[i][j], 0, 0, 0);
    }
  }

  if (OUT_BF16) {
    ushort_t* C = (ushort_t*)Cout;
#pragma unroll
    for (int i = 0; i < 4; ++i)
#pragma unroll
      for (int j = 0; j < 4; ++j) {
        const int col = n0 + wn + j * 16 + (lane & 15);
#pragma unroll
        for (int r = 0; r < 4; ++r) {
          const int row = m0 + wm + i * 16 + (lane >> 4) * 4 + r;
          C[(size_t)row * N + col] = f2b(acc[i][j][r]);
        }
      }
  } else {
    float* C = (float*)Cout;
#pragma unroll
    for (int i = 0; i < 4; ++i)
#pragma unroll
      for (int j = 0; j < 4; ++j) {
        const int col = n0 + wn + j * 16 + (lane & 15);
        const float bv = bias ? bias[col] : 0.f;
#pragma unroll
        for (int r = 0; r < 4; ++r) {
          const int row = m0 + wm + i * 16 + (lane >> 4) * 4 + r;
          C[(size_t)row * N + col] = acc[i][j][r] + bv;
        }
      }
  }
}

// ---------------------------------------------------------------------------
// bf16-MFMA flash attention — unchanged from round 11 (passing, conflict-free)
// ---------------------------------------------------------------------------
#define KVB 64
#define QPW 32
#define QPB 256
#define NT  (SEQ / KVB)

__global__ __launch_bounds__(512) void attn_mfma(const ushort_t* __restrict__ QKV,
                                                 ushort_t* __restrict__ Aout) {
  const int bh = blockIdx.x;   // fast dim: q-tiles of one (b,h) share an XCD
  const int qt = blockIdx.y;
  const int b = bh >> 4, h = bh & 15;
  const int tid  = threadIdx.x;
  const int w    = tid >> 6;      // 0..7
  const int lane = tid & 63;
  const int l31  = lane & 31;
  const int hi   = lane >> 5;

  __shared__ __align__(16) ushort_t Kfrag[6 * 64 * 8];  // 6 KB [slot][pos^slot][8]
  __shared__ __align__(16) ushort_t Vt2[8 * 65 * 8];    // 8.1 KB [kb][hd(pad65)][key%8]

  // zero Vt2, BARRIER, then ones row hd=48 (l accumulator row)
  *(uint4*)&Vt2[tid * 8] = make_uint4(0u, 0u, 0u, 0u);
  if (tid < 8) *(uint4*)&Vt2[4096 + tid * 8] = make_uint4(0u, 0u, 0u, 0u);
  __syncthreads();
  if (tid < 64) Vt2[((tid >> 3) * 65 + 48) * 8 + (tid & 7)] = (ushort_t)0x3F80;

  const ushort_t* qkv_b = QKV + (size_t)b * SEQ * QKVD;

  // --- Q fragments, pre-scaled by SCALE*log2(e) ---
  const float qs = 0.14433756729740643f * 1.44269504088896340f;
  const int qrow = qt * QPB + w * QPW + l31;
  const ushort_t* qsrc = qkv_b + (size_t)qrow * QKVD + h * HD;
  s16x8 qf[3];
#pragma unroll
  for (int ks = 0; ks < 3; ++ks) {
    s16x8 raw = *(const s16x8*)(qsrc + ks * 16 + hi * 8);
    s16x8 v;
#pragma unroll
    for (int j = 0; j < 8; ++j) v[j] = (short)f2b(b2f((unsigned short)raw[j]) * qs);
    qf[ks] = v;
  }

  f32x16 o[2];
#pragma unroll
  for (int mt = 0; mt < 2; ++mt)
#pragma unroll
    for (int r = 0; r < 16; ++r) o[mt][r] = 0.f;

  // staging: lane = key row; wave w = hd-granule (waves 0..5 only)
  const int srow = lane;
  const int g0 = w;
  const ushort_t* kv0 = qkv_b + (size_t)srow * QKVD + DIMD + h * HD;

  s16x8 ka, va;
  auto loadKV = [&](int kt) {
    if (g0 < 6) {
      const ushort_t* base = kv0 + (size_t)(kt * KVB) * QKVD;
      ka = *(const s16x8*)(base + g0 * 8);
      va = *(const s16x8*)(base + DIMD + g0 * 8);
    }
  };
  auto writeKV = [&]() {
    if (g0 < 6) {
      const int slot = (srow >> 5) * 3 + (g0 >> 1);
      const int pos = (((srow & 31) + ((g0 & 1) << 5)) ^ slot);
      *(s16x8*)&Kfrag[(slot * 64 + pos) * 8] = ka;
      const int kb = srow >> 3, k7 = srow & 7;
#pragma unroll
      for (int j = 0; j < 8; ++j)
        Vt2[(kb * 65 + 8 * g0 + j) * 8 + k7] = (ushort_t)va[j];
    }
  };

  loadKV(0);

  for (int kt = 0; kt < NT; ++kt) {
    __syncthreads();   // LDS readers of previous tile done
    writeKV();
    __syncthreads();   // K/V tile ready
    if (kt + 1 < NT) loadKV(kt + 1);   // T14: lands during compute

    // ---- QK^T swapped: S^T[key][q], two 32-key halves ----
    f32x16 s0, s1;
#pragma unroll
    for (int r = 0; r < 16; ++r) { s0[r] = 0.f; s1[r] = 0.f; }
    __builtin_amdgcn_s_setprio(1);
#pragma unroll
    for (int ks = 0; ks < 3; ++ks) {
      s16x8 a0 = *(const s16x8*)&Kfrag[(ks * 64 + (lane ^ ks)) * 8];
      s0 = __builtin_amdgcn_mfma_f32_32x32x16_bf16(a0, qf[ks], s0, 0, 0, 0);
      s16x8 a1 = *(const s16x8*)&Kfrag[((3 + ks) * 64 + (lane ^ (3 + ks))) * 8];
      s1 = __builtin_amdgcn_mfma_f32_32x32x16_bf16(a1, qf[ks], s1, 0, 0, 0);
    }
    __builtin_amdgcn_s_setprio(0);

    // ---- softmax numerator: exp2 raw (logits bounded), pack to bf16 ----
    unsigned pw0[8], pw1[8];
#pragma unroll
    for (int g = 0; g < 8; ++g) {
      pw0[g] = pk2(__builtin_amdgcn_exp2f(s0[2 * g]),
                   __builtin_amdgcn_exp2f(s0[2 * g + 1]));
      pw1[g] = pk2(__builtin_amdgcn_exp2f(s1[2 * g]),
                   __builtin_amdgcn_exp2f(s1[2 * g + 1]));
    }

    // ---- PV: O^T += V^T @ P^T ; P^T B-frags via permlane32_swap ----
    __builtin_amdgcn_s_setprio(1);
#pragma unroll
    for (int ks = 0; ks < 4; ++ks) {
      unsigned w0 = (ks < 2) ? pw0[4 * (ks & 1) + 0] : pw1[4 * (ks & 1) + 0];
      unsigned w1 = (ks < 2) ? pw0[4 * (ks & 1) + 1] : pw1[4 * (ks & 1) + 1];
      unsigned w2 = (ks < 2) ? pw0[4 * (ks & 1) + 2] : pw1[4 * (ks & 1) + 2];
      unsigned w3 = (ks < 2) ? pw0[4 * (ks & 1) + 3] : pw1[4 * (ks & 1) + 3];
      asm("v_permlane32_swap_b32 %0, %1" : "+v"(w0), "+v"(w2));
      asm("v_permlane32_swap_b32 %0, %1" : "+v"(w1), "+v"(w3));
      union { unsigned u[4]; s16x8 v; } pf;
      pf.u[0] = w0; pf.u[1] = w1; pf.u[2] = w2; pf.u[3] = w3;
      const int kb = 2 * ks + hi;   // key-block = (ks*16 + hi*8) / 8
#pragma unroll
      for (int mt = 0; mt < 2; ++mt) {
        const int hd = mt * 32 + l31;
        s16x8 vfrag = *(const s16x8*)&Vt2[(kb * 65 + hd) * 8];
        o[mt] = __builtin_amdgcn_mfma_f32_32x32x16_bf16(vfrag, pf.v, o[mt], 0, 0, 0);
      }
    }
    __builtin_amdgcn_s_setprio(0);
  }

  // ---- epilogue: l = o[1][8] (hd 48 = ones row, hi=0 half); normalize ----
  const float lsum = __shfl(o[1][8], l31, 64);
  const float inv = 1.f / lsum;
  const int token = qt * QPB + w * QPW + l31;
  ushort_t* dst = Aout + ((size_t)b * SEQ + token) * DIMD + h * HD;
#pragma unroll
  for (int rq = 0; rq < 4; ++rq) {      // m-tile0: hd = 8*rq + 4*hi + {0..3}
    const int hd0 = 8 * rq + 4 * hi;
    uint2 pk;
    pk.x = pk2(o[0][4 * rq + 0] * inv, o[0][4 * rq + 1] * inv);
    pk.y = pk2(o[0][4 * rq + 2] * inv, o[0][4 * rq + 3] * inv);
    *(uint2*)(dst + hd0) = pk;
  }
#pragma unroll
  for (int rq = 0; rq < 2; ++rq) {      // m-tile1: hd = 32 + 8*rq + 4*hi + {0..3}
    const int hd0 = 32 + 8 * rq + 4 * hi;
    uint2 pk;
    pk.x = pk2(o[1][4 * rq + 0] * inv, o[1][4 * rq + 1] * inv);
    pk.y = pk2(o[1][4 * rq + 2] * inv, o[1][4 * rq + 3] * inv);
    *(uint2*)(dst + hd0) = pk;
  }
}

// ---------------------------------------------------------------------------
extern "C" void kernel_launch(void* const* d_in, const int* in_sizes, int n_in,
                              void* d_out, int out_size, void* d_ws, size_t ws_size,
                              hipStream_t stream) {
  const float* x      = (const float*)d_in[0];
  const float* w_qkv  = (const float*)d_in[1];
  const float* w_proj = (const float*)d_in[2];
  const float* b_proj = (const float*)d_in[3];
  float* out = (float*)d_out;

  ushort_t* xb     = (ushort_t*)d_ws;                  // [8192,768]  bf16
  ushort_t* wqkvT  = xb + (size_t)NTOK * DIMD;         // [2304,768]  bf16 (T)
  ushort_t* wprojT = wqkvT + (size_t)QKVD * DIMD;      // [768,768]   bf16 (T)
  ushort_t* qkv    = wprojT + (size_t)DIMD * DIMD;     // [8192,2304] bf16
  ushort_t* att    = qkv + (size_t)NTOK * QKVD;        // [8192,768]  bf16

  // one merged convert launch (x cvt + both weight transposes)
  cvt_all<<<CVT_NB + TQ_NB + TP_NB, 256, 0, stream>>>(
      x, xb, w_qkv, wqkvT, w_proj, wprojT);

  gemm_bf16<1><<<dim3(QKVD / 128, NTOK / 128), 256, 0, stream>>>(
      xb, wqkvT, nullptr, qkv, NTOK, QKVD, DIMD);

  attn_mfma<<<dim3(BATCH * HEADS, SEQ / QPB), 512, 0, stream>>>(qkv, att);

  gemm_bf16<0><<<dim3(DIMD / 128, NTOK / 128), 256, 0, stream>>>(
      att, wprojT, b_proj, out, NTOK, DIMD, DIMD);
}